// Round 1
// baseline (276.174 us; speedup 1.0000x reference)
//
#include <hip/hip_runtime.h>
#include <hip/hip_bf16.h>

#define B_   2
#define C_   256
#define HW_  25600
#define N_   2048
#define NH_  8
#define DH_  32
#define NCHUNK 100   // HW_/256

typedef __attribute__((ext_vector_type(8))) short short8;
typedef __attribute__((ext_vector_type(4))) float f32x4;

__device__ inline unsigned short f2b(float f) {
    union { float f; unsigned u; } v; v.f = f;
    unsigned r = v.u + 0x7fffu + ((v.u >> 16) & 1u);
    return (unsigned short)(r >> 16);
}

__device__ inline f32x4 mfma16(short8 a, short8 b, f32x4 c) {
    return __builtin_amdgcn_mfma_f32_16x16x32_bf16(a, b, c, 0, 0, 0);
}

// ---------------------------------------------------------------- zero out
__global__ __launch_bounds__(256) void zero_kernel(float4* out, int n4) {
    int i = blockIdx.x * 256 + threadIdx.x;
    if (i < n4) out[i] = make_float4(0.f, 0.f, 0.f, 0.f);
}

// ------------------------------------------------- stage A: flags + counts
__global__ __launch_bounds__(256) void flags_count_kernel(const float* __restrict__ x,
                                                          int* __restrict__ flags,
                                                          int* __restrict__ counts) {
    int b = blockIdx.y, chunk = blockIdx.x, tid = threadIdx.x;
    int p = chunk * 256 + tid;
    const float* xb = x + (size_t)b * C_ * HW_ + p;
    int f = 0;
#pragma unroll 16
    for (int c = 0; c < C_; ++c) f |= (xb[(size_t)c * HW_] != 0.f) ? 1 : 0;
    flags[b * HW_ + p] = f;
    int s = f;
#pragma unroll
    for (int off = 1; off < 64; off <<= 1) s += __shfl_xor(s, off);
    __shared__ int red4[4];
    if ((tid & 63) == 0) red4[tid >> 6] = s;
    __syncthreads();
    if (tid == 0) counts[b * NCHUNK + chunk] = red4[0] + red4[1] + red4[2] + red4[3];
}

// ------------------------------------------------- stage B: scan of counts
__global__ __launch_bounds__(256) void scan_counts_kernel(const int* __restrict__ counts,
                                                          int* __restrict__ offs) {
    __shared__ int sc[2][128];
    int h = threadIdx.x >> 7, i = threadIdx.x & 127;
    int v = (i < NCHUNK) ? counts[h * NCHUNK + i] : 0;
    sc[h][i] = v;
    __syncthreads();
    for (int off = 1; off < 128; off <<= 1) {
        int t = (i >= off) ? sc[h][i - off] : 0;
        __syncthreads();
        sc[h][i] += t;
        __syncthreads();
    }
    if (i < NCHUNK) offs[h * NCHUNK + i] = sc[h][i] - v;  // exclusive
}

// ------------------------------------------------- stage C: scatter indices
__global__ __launch_bounds__(256) void scatter_idx_kernel(const int* __restrict__ flags,
                                                          const int* __restrict__ offs,
                                                          int* __restrict__ idx) {
    int b = blockIdx.y, chunk = blockIdx.x, tid = threadIdx.x;
    int p = chunk * 256 + tid;
    int f = flags[b * HW_ + p];
    __shared__ int sc[256];
    sc[tid] = f;
    __syncthreads();
    for (int off = 1; off < 256; off <<= 1) {
        int t = (tid >= off) ? sc[tid - off] : 0;
        __syncthreads();
        sc[tid] += t;
        __syncthreads();
    }
    if (f) {
        int pos = offs[b * NCHUNK + chunk] + sc[tid] - 1;
        if (pos < N_) idx[b * N_ + pos] = p;
    }
}

// ---------------------------------------------------------------- gather
__global__ __launch_bounds__(256) void gather_kernel(const float* __restrict__ x,
                                                     const int* __restrict__ idx,
                                                     float* __restrict__ tokf,
                                                     unsigned short* __restrict__ tokb) {
    int t = blockIdx.x;         // b*N_ + n
    int b = t >> 11;
    int c = threadIdx.x;
    int p = idx[t];
    if (p < 0 || p >= HW_) p = 0;   // safety (should not happen)
    float v = x[(size_t)b * C_ * HW_ + (size_t)c * HW_ + p];
    tokf[(size_t)t * C_ + c] = v;
    tokb[(size_t)t * C_ + c] = f2b(v);
}

// ------------------------------------------- weight transpose+cast to bf16
__global__ __launch_bounds__(256) void wt_kernel(const float* __restrict__ Wq,
                                                 const float* __restrict__ Wk,
                                                 const float* __restrict__ Wv,
                                                 const float* __restrict__ Wo,
                                                 unsigned short* __restrict__ WT) {
    int j = blockIdx.x, m = blockIdx.y, c = threadIdx.x;
    const float* Wm = (m == 0) ? Wq : (m == 1) ? Wk : (m == 2) ? Wv : Wo;
    // WT[m][j][c] = W[c][j]   (transposed so B-fragments are contiguous in k)
    WT[((size_t)m * C_ + j) * C_ + c] = f2b(Wm[(size_t)c * C_ + j]);
}

// ---------------------------------------------------------- QKV projection
__global__ __launch_bounds__(256) void qkv_gemm_kernel(const unsigned short* __restrict__ tokb,
                                                       const unsigned short* __restrict__ WT,
                                                       const float* __restrict__ bq,
                                                       const float* __restrict__ bk,
                                                       const float* __restrict__ bv,
                                                       unsigned short* __restrict__ Qb,
                                                       unsigned short* __restrict__ Kb,
                                                       unsigned short* __restrict__ Vtb) {
    int z = blockIdx.z;
    int m = z >> 1;        // 0=Q 1=K 2=V
    int b = z & 1;
    int w = threadIdx.x >> 6, lane = threadIdx.x & 63;
    int col = lane & 15, quad = lane >> 4;
    int row0 = blockIdx.x * 64 + w * 16;
    int j0 = blockIdx.y * 64;
    const unsigned short* A = tokb + (size_t)b * N_ * C_;
    const unsigned short* Wm = WT + (size_t)m * C_ * C_;
    f32x4 acc[4];
#pragma unroll
    for (int jt = 0; jt < 4; ++jt) acc[jt] = (f32x4){0.f, 0.f, 0.f, 0.f};
#pragma unroll
    for (int kk = 0; kk < C_; kk += 32) {
        short8 a = *(const short8*)(A + (size_t)(row0 + col) * C_ + kk + quad * 8);
#pragma unroll
        for (int jt = 0; jt < 4; ++jt) {
            short8 bf = *(const short8*)(Wm + (size_t)(j0 + jt * 16 + col) * C_ + kk + quad * 8);
            acc[jt] = mfma16(a, bf, acc[jt]);
        }
    }
    const float* bias = (m == 0) ? bq : (m == 1) ? bk : bv;
#pragma unroll
    for (int jt = 0; jt < 4; ++jt) {
#pragma unroll
        for (int r = 0; r < 4; ++r) {
            int row = row0 + quad * 4 + r;
            int jc = j0 + jt * 16 + col;
            float v = acc[jt][r] + bias[jc];
            if (m == 0) {
                v *= 0.17677669529663687f;   // 1/sqrt(32) folded into Q
                Qb[((size_t)b * N_ + row) * C_ + jc] = f2b(v);
            } else if (m == 1) {
                Kb[((size_t)b * N_ + row) * C_ + jc] = f2b(v);
            } else {
                Vtb[((size_t)b * C_ + jc) * N_ + row] = f2b(v);  // V transposed (c,n)
            }
        }
    }
}

// ------------------------------------------------------- flash attention
__global__ __launch_bounds__(256) void attn_kernel(const unsigned short* __restrict__ Qb,
                                                   const unsigned short* __restrict__ Kb,
                                                   const unsigned short* __restrict__ Vtb,
                                                   unsigned short* __restrict__ Ob) {
    int b = blockIdx.z, h = blockIdx.y;
    int w = threadIdx.x >> 6, lane = threadIdx.x & 63;
    int col = lane & 15, quad = lane >> 4;
    int q0 = blockIdx.x * 64 + w * 16;

    __shared__ __attribute__((aligned(16))) unsigned short p_lds[4][16][32];

    const unsigned short* Qp = Qb + (size_t)b * N_ * C_;
    const unsigned short* Kp = Kb + (size_t)b * N_ * C_;
    const unsigned short* Vp = Vtb + (size_t)b * C_ * N_;
    unsigned short* Op = Ob + (size_t)b * N_ * C_;

    short8 qfrag = *(const short8*)(Qp + (size_t)(q0 + col) * C_ + h * DH_ + quad * 8);

    float m_run[4], l_run[4];
#pragma unroll
    for (int r = 0; r < 4; ++r) { m_run[r] = -1e30f; l_run[r] = 0.f; }
    f32x4 accO[2];
    accO[0] = (f32x4){0.f, 0.f, 0.f, 0.f};
    accO[1] = (f32x4){0.f, 0.f, 0.f, 0.f};

    for (int mt = 0; mt < N_; mt += 32) {
        f32x4 S[2];
#pragma unroll
        for (int t = 0; t < 2; ++t) {
            short8 kf = *(const short8*)(Kp + (size_t)(mt + t * 16 + col) * C_ + h * DH_ + quad * 8);
            S[t] = mfma16(qfrag, kf, (f32x4){0.f, 0.f, 0.f, 0.f});
        }
        float pv[2][4], alpha[4];
#pragma unroll
        for (int r = 0; r < 4; ++r) {
            float mx = fmaxf(S[0][r], S[1][r]);
#pragma unroll
            for (int off = 1; off < 16; off <<= 1) mx = fmaxf(mx, __shfl_xor(mx, off));
            float mnew = fmaxf(m_run[r], mx);
            alpha[r] = __expf(m_run[r] - mnew);
            m_run[r] = mnew;
            float p0 = __expf(S[0][r] - mnew);
            float p1 = __expf(S[1][r] - mnew);
            float s = p0 + p1;
#pragma unroll
            for (int off = 1; off < 16; off <<= 1) s += __shfl_xor(s, off);
            l_run[r] = l_run[r] * alpha[r] + s;
            pv[0][r] = p0;
            pv[1][r] = p1;
        }
#pragma unroll
        for (int t = 0; t < 2; ++t)
#pragma unroll
            for (int r = 0; r < 4; ++r) accO[t][r] *= alpha[r];

        __syncthreads();   // guard WAR on p_lds across iterations
#pragma unroll
        for (int t = 0; t < 2; ++t)
#pragma unroll
            for (int r = 0; r < 4; ++r)
                p_lds[w][quad * 4 + r][t * 16 + col] = f2b(pv[t][r]);
        __syncthreads();

        short8 pfrag = *(const short8*)(&p_lds[w][col][quad * 8]);
#pragma unroll
        for (int t = 0; t < 2; ++t) {
            short8 vf = *(const short8*)(Vp + (size_t)(h * DH_ + t * 16 + col) * N_ + mt + quad * 8);
            accO[t] = mfma16(pfrag, vf, accO[t]);
        }
    }
#pragma unroll
    for (int t = 0; t < 2; ++t)
#pragma unroll
        for (int r = 0; r < 4; ++r) {
            float o = accO[t][r] / l_run[r];
            Op[(size_t)(q0 + quad * 4 + r) * C_ + h * DH_ + t * 16 + col] = f2b(o);
        }
}

// ------------------------------------------------------------ O projection
__global__ __launch_bounds__(256) void oproj_gemm_kernel(const unsigned short* __restrict__ Ob,
                                                         const unsigned short* __restrict__ WT,
                                                         const float* __restrict__ bo,
                                                         float* __restrict__ yf) {
    int b = blockIdx.z;
    int w = threadIdx.x >> 6, lane = threadIdx.x & 63;
    int col = lane & 15, quad = lane >> 4;
    int row0 = blockIdx.x * 64 + w * 16;
    int j0 = blockIdx.y * 64;
    const unsigned short* A = Ob + (size_t)b * N_ * C_;
    const unsigned short* Wm = WT + (size_t)3 * C_ * C_;
    f32x4 acc[4];
#pragma unroll
    for (int jt = 0; jt < 4; ++jt) acc[jt] = (f32x4){0.f, 0.f, 0.f, 0.f};
#pragma unroll
    for (int kk = 0; kk < C_; kk += 32) {
        short8 a = *(const short8*)(A + (size_t)(row0 + col) * C_ + kk + quad * 8);
#pragma unroll
        for (int jt = 0; jt < 4; ++jt) {
            short8 bf = *(const short8*)(Wm + (size_t)(j0 + jt * 16 + col) * C_ + kk + quad * 8);
            acc[jt] = mfma16(a, bf, acc[jt]);
        }
    }
#pragma unroll
    for (int jt = 0; jt < 4; ++jt) {
#pragma unroll
        for (int r = 0; r < 4; ++r) {
            int row = row0 + quad * 4 + r;
            int jc = j0 + jt * 16 + col;
            yf[((size_t)b * N_ + row) * C_ + jc] = acc[jt][r] + bo[jc];
        }
    }
}

// -------------------------------------------- residual + LayerNorm + scatter
__global__ __launch_bounds__(256) void epilogue_kernel(const float* __restrict__ tokf,
                                                       const float* __restrict__ yf,
                                                       const int* __restrict__ idx,
                                                       const float* __restrict__ gamma,
                                                       const float* __restrict__ beta,
                                                       float* __restrict__ out) {
    int t = blockIdx.x;      // b*N_ + n
    int b = t >> 11;
    int c = threadIdx.x;
    float z = tokf[(size_t)t * C_ + c] + yf[(size_t)t * C_ + c];
    float s = z, s2 = z * z;
#pragma unroll
    for (int off = 1; off < 64; off <<= 1) {
        s += __shfl_xor(s, off);
        s2 += __shfl_xor(s2, off);
    }
    __shared__ float red[2][4];
    int w = c >> 6, lane = c & 63;
    if (lane == 0) { red[0][w] = s; red[1][w] = s2; }
    __syncthreads();
    s = red[0][0] + red[0][1] + red[0][2] + red[0][3];
    s2 = red[1][0] + red[1][1] + red[1][2] + red[1][3];
    float mu = s * (1.f / C_);
    float var = s2 * (1.f / C_) - mu * mu;
    float rstd = rsqrtf(var + 1e-5f);
    float r = (z - mu) * rstd * gamma[c] + beta[c];
    int p = idx[t];
    if (p < 0 || p >= HW_) p = 0;    // safety
    out[(size_t)b * C_ * HW_ + (size_t)c * HW_ + p] = r;
}

extern "C" void kernel_launch(void* const* d_in, const int* in_sizes, int n_in,
                              void* d_out, int out_size, void* d_ws, size_t ws_size,
                              hipStream_t stream) {
    const float* x     = (const float*)d_in[0];
    const float* Wq    = (const float*)d_in[1];
    const float* bq    = (const float*)d_in[2];
    const float* Wk    = (const float*)d_in[3];
    const float* bk    = (const float*)d_in[4];
    const float* Wv    = (const float*)d_in[5];
    const float* bv    = (const float*)d_in[6];
    const float* Wo    = (const float*)d_in[7];
    const float* bo    = (const float*)d_in[8];
    const float* gamma = (const float*)d_in[9];
    const float* beta  = (const float*)d_in[10];
    float* out = (float*)d_out;

    char* ws = (char*)d_ws;
    size_t off = 0;
    auto alloc = [&](size_t bytes) {
        size_t o = off;
        off += (bytes + 255) & ~(size_t)255;
        return o;
    };
    int* flags   = (int*)(ws + alloc((size_t)B_ * HW_ * 4));
    int* counts  = (int*)(ws + alloc((size_t)B_ * NCHUNK * 4));
    int* offs    = (int*)(ws + alloc((size_t)B_ * NCHUNK * 4));
    int* idx     = (int*)(ws + alloc((size_t)B_ * N_ * 4));
    float* tokf  = (float*)(ws + alloc((size_t)B_ * N_ * C_ * 4));
    unsigned short* tokb = (unsigned short*)(ws + alloc((size_t)B_ * N_ * C_ * 2));
    unsigned short* WT   = (unsigned short*)(ws + alloc((size_t)4 * C_ * C_ * 2));
    unsigned short* Qb   = (unsigned short*)(ws + alloc((size_t)B_ * N_ * C_ * 2));
    unsigned short* Kb   = (unsigned short*)(ws + alloc((size_t)B_ * N_ * C_ * 2));
    unsigned short* Vtb  = (unsigned short*)(ws + alloc((size_t)B_ * C_ * N_ * 2));
    unsigned short* Ob   = (unsigned short*)(ws + alloc((size_t)B_ * N_ * C_ * 2));
    float* yf    = (float*)(ws + alloc((size_t)B_ * N_ * C_ * 4));
    (void)ws_size; (void)n_in; (void)in_sizes;

    int n4 = out_size / 4;
    zero_kernel<<<dim3((n4 + 255) / 256), 256, 0, stream>>>((float4*)out, n4);
    flags_count_kernel<<<dim3(NCHUNK, B_), 256, 0, stream>>>(x, flags, counts);
    scan_counts_kernel<<<1, 256, 0, stream>>>(counts, offs);
    scatter_idx_kernel<<<dim3(NCHUNK, B_), 256, 0, stream>>>(flags, offs, idx);
    gather_kernel<<<B_ * N_, 256, 0, stream>>>(x, idx, tokf, tokb);
    wt_kernel<<<dim3(C_, 4), 256, 0, stream>>>(Wq, Wk, Wv, Wo, WT);
    qkv_gemm_kernel<<<dim3(N_ / 64, C_ / 64, 6), 256, 0, stream>>>(tokb, WT, bq, bk, bv, Qb, Kb, Vtb);
    attn_kernel<<<dim3(N_ / 64, NH_, B_), 256, 0, stream>>>(Qb, Kb, Vtb, Ob);
    oproj_gemm_kernel<<<dim3(N_ / 64, C_ / 64, B_), 256, 0, stream>>>(Ob, WT, bo, yf);
    epilogue_kernel<<<B_ * N_, 256, 0, stream>>>(tokf, yf, idx, gamma, beta, out);
}